// Round 12
// baseline (314.769 us; speedup 1.0000x reference)
//
#include <hip/hip_runtime.h>
#include <cstdint>
#include <cstddef>

static constexpr float NEG_SLOPE_C = 0.2f;
static constexpr float EPS_C = 1e-16f;
static constexpr float LOG2E_C = 1.4426950408889634f;
// att·leaky(v) = 0.6(att·v) + 0.4(att·|v|); fold log2(e) for exp2 domain
static constexpr float QA_C = 0.6f * LOG2E_C;
static constexpr float QB_C = 0.4f * LOG2E_C;

#if defined(__has_builtin)
#if __has_builtin(__builtin_amdgcn_exp2f)
#define EXP2F(x) __builtin_amdgcn_exp2f(x)
#else
#define EXP2F(x) exp2f(x)
#endif
#else
#define EXP2F(x) exp2f(x)
#endif

typedef __attribute__((ext_vector_type(8))) short bf16x8;
typedef __attribute__((ext_vector_type(4))) float f32x4;
typedef __attribute__((ext_vector_type(2))) float f32x2;

__device__ __forceinline__ short bf16_rne(float x) {
    unsigned u = __float_as_uint(x);
    u = (u + 0x7FFF + ((u >> 16) & 1)) >> 16;
    return (short)u;
}
__device__ __forceinline__ float bf16f(short s) {
    return __uint_as_float(((unsigned)(unsigned short)s) << 16);
}

// DPP-based partial-sum add: v += dpp_perm(v).
template<int CTRL>
__device__ __forceinline__ float dpp_add_f(float v) {
    int x = __builtin_amdgcn_update_dpp(0, __float_as_int(v), CTRL, 0xf, 0xf, true);
    return v + __int_as_float(x);
}

// Reduce within each aligned 8-lane group (3 DPP steps, no DS).
__device__ __forceinline__ float reduce8(float q) {
    q = dpp_add_f<0xB1>(q);      // xor1 (quad_perm [1,0,3,2])
    q = dpp_add_f<0x4E>(q);      // xor2 (quad_perm [2,3,0,1])
    q = dpp_add_f<0x141>(q);     // row_half_mirror: crosses the two quads of 8
    return q;
}

// 8 channels as 4 packed float2 (pk-fp32 friendly)
struct v8 { f32x2 h[4]; };
__device__ __forceinline__ v8 load8(const float4* base, int idx) {
    v8 r;
    const float4 a = base[idx];
    const float4 b = base[idx + 1];
    r.h[0] = (f32x2){a.x, a.y}; r.h[1] = (f32x2){a.z, a.w};
    r.h[2] = (f32x2){b.x, b.y}; r.h[3] = (f32x2){b.z, b.w};
    return r;
}

// ---------------- CSR construction ----------------

__global__ void degree_kernel(const int* __restrict__ ei, const float* __restrict__ ew,
                              int E, int* __restrict__ cnt, float* __restrict__ wsum) {
    int e = blockIdx.x * blockDim.x + threadIdx.x;
    if (e >= E) return;
    int dst = ei[E + e];
    atomicAdd(&cnt[dst], 1);
    atomicAdd(&wsum[dst], ew[e]);
}

__global__ void scan_kernel(const int* __restrict__ cnt, const float* __restrict__ wsum,
                            int N, int E, int* __restrict__ offs, float* __restrict__ self_w) {
    __shared__ int bufA[1024];
    __shared__ int bufB[1024];
    int t = threadIdx.x;
    int chunk = (N + 1023) / 1024;
    int lo = t * chunk;
    int hi = lo + chunk; if (hi > N) hi = N; if (lo > N) lo = N;
    int s = 0;
    for (int n = lo; n < hi; ++n) s += cnt[n];
    bufA[t] = s;
    __syncthreads();
    int* srcb = bufA; int* dstb = bufB;
    for (int d = 1; d < 1024; d <<= 1) {
        int v = srcb[t];
        if (t >= d) v += srcb[t - d];
        dstb[t] = v;
        __syncthreads();
        int* tmp = srcb; srcb = dstb; dstb = tmp;
    }
    int run = (t == 0) ? 0 : srcb[t - 1];
    for (int n = lo; n < hi; ++n) { offs[n] = run; run += cnt[n]; }
    if (t == 0) offs[N] = E;
    for (int n = t; n < N; n += 1024) {
        int c = cnt[n];
        self_w[n] = (c > 0) ? (wsum[n] / (float)c) : 0.0f;
    }
}

__global__ void scatter_kernel(const int* __restrict__ ei, const float* __restrict__ ew, int E,
                               const int* __restrict__ offs, int* __restrict__ cursor,
                               int2* __restrict__ pairs) {
    int e = blockIdx.x * blockDim.x + threadIdx.x;
    if (e >= E) return;
    int dst = ei[E + e];
    int pos = offs[dst] + atomicAdd(&cursor[dst], 1);
    pairs[pos] = make_int2(ei[e], __float_as_int(ew[e]));
}

// ---------------- W prep: fp32 -> split-bf16 hi/lo in MFMA FRAGMENT ORDER -----

template<int K>
__global__ void wprep_kernel(const float* __restrict__ Wl, const float* __restrict__ Wr,
                             uint4* __restrict__ Wf) {
    const int gid = blockIdx.x * 256 + threadIdx.x;   // (K/32)*16*64 threads
    const int lane = gid & 63;
    const int t = (gid >> 6) & 15;
    const int s = gid >> 10;
    const int mr = lane & 15, q = lane >> 4;
    const int col = t * 16 + mr;
    const float* src = (col < 128) ? (Wl + col) : (Wr + col - 128);
    union { short sh[8]; uint4 u; } hv, lv;
    #pragma unroll
    for (int j = 0; j < 8; ++j) {
        const float v = src[(size_t)(s * 32 + q * 8 + j) * 128];
        const short h = bf16_rne(v);
        hv.sh[j] = h;
        lv.sh[j] = bf16_rne(v - bf16f(h));
    }
    const size_t base = (size_t)s * 2048 + (size_t)(t * 2) * 64 + lane;
    Wf[base] = hv.u;          // hi plane
    Wf[base + 64] = lv.u;     // lo plane
}

// ---------------- split-bf16 MFMA GEMM (R10-proven, unchanged) ----------------

template<int K>
__global__ __launch_bounds__(256) void gemm_mfma_kernel(
    const float* __restrict__ X, const uint4* __restrict__ Wf,
    float* __restrict__ outL, float* __restrict__ outR) {
    __shared__ uint4 wbuf[2048];          // 32 KB: one k-slice, fragment order
    const int tid = threadIdx.x;
    const int wv = tid >> 6;
    const int lane = tid & 63;
    const int q = lane >> 4;
    const int mr = lane & 15;
    const int xrow = blockIdx.x * 64 + wv * 16 + mr;

    f32x4 acc[16];
    #pragma unroll
    for (int t = 0; t < 16; ++t) acc[t] = (f32x4){0.f, 0.f, 0.f, 0.f};

    const float* xp = X + (size_t)xrow * K + q * 8;

    for (int s = 0; s < K / 32; ++s) {
        const float4 a0 = *(const float4*)(xp + s * 32);
        const float4 a1 = *(const float4*)(xp + s * 32 + 4);

        __syncthreads();                   // previous slice fully consumed
        const uint4* gsrc = Wf + (size_t)s * 2048 + wv * 512 + lane;
        #pragma unroll
        for (int i = 0; i < 8; ++i)
            wbuf[wv * 512 + i * 64 + lane] = gsrc[i * 64];
        __syncthreads();                   // slice visible

        const float av[8] = {a0.x, a0.y, a0.z, a0.w, a1.x, a1.y, a1.z, a1.w};
        bf16x8 xh, xl;
        #pragma unroll
        for (int j = 0; j < 8; ++j) {
            const short h = bf16_rne(av[j]);
            xh[j] = h;
            xl[j] = bf16_rne(av[j] - bf16f(h));
        }
        #pragma unroll
        for (int t = 0; t < 16; ++t) {
            const bf16x8 wh = *(const bf16x8*)&wbuf[(t * 2) * 64 + lane];
            const bf16x8 wl = *(const bf16x8*)&wbuf[(t * 2 + 1) * 64 + lane];
            acc[t] = __builtin_amdgcn_mfma_f32_16x16x32_bf16(wh, xh, acc[t], 0, 0, 0);
            acc[t] = __builtin_amdgcn_mfma_f32_16x16x32_bf16(wl, xh, acc[t], 0, 0, 0);
            acc[t] = __builtin_amdgcn_mfma_f32_16x16x32_bf16(wh, xl, acc[t], 0, 0, 0);
        }
    }

    const size_t ob = (size_t)xrow * 128 + q * 4;
    #pragma unroll
    for (int t = 0; t < 8; ++t) {
        *(float4*)(outL + ob + t * 16) =
            make_float4(acc[t][0], acc[t][1], acc[t][2], acc[t][3]);
        *(float4*)(outR + ob + t * 16) =
            make_float4(acc[t + 8][0], acc[t + 8][1], acc[t + 8][2], acc[t + 8][3]);
    }
}

// ---------------- fused edge softmax-aggregate: FOUR edges per wave -----------
// Lane l: edge slot p = l>>4, within-edge lane u = l&15, channels u*8..u*8+7
// (head 0 = u<8, head 1 = u>=8). Per-head dot = reduce8 (3 DPP) serving all
// 4 edges at once. Channel math in packed float2 (v_pk_fma_f32 path):
// att·leaky(v) = 0.6(att·v) + 0.4(att·|v|) -- two pk-fma dot accumulators,
// abs via AND, no pk-min needed. Masked lanes replace tail code. Self-loop
// contributes 0.25x from each slot (exact). XCD swizzle (R7-proven) unchanged.

__global__ __launch_bounds__(256) void edge_kernel(
    const float* __restrict__ xl, const float* __restrict__ xr,
    const int* __restrict__ offs, const int2* __restrict__ pairs,
    const float* __restrict__ self_w,
    const float* __restrict__ att, const float* __restrict__ We,
    const float* __restrict__ bias, float* __restrict__ out,
    int N, int M) {
    const int wave = __builtin_amdgcn_readfirstlane(threadIdx.x >> 6);
    const int b = blockIdx.x;
    const int hb = (b >= 10000) ? (b - 10000) : b;
    const int m = ((b >= 10000) ? 8 : 0) + (hb & 7);
    const int n = (hb >> 3) * 4 + wave;
    if (n >= N) return;
    const int lane = threadIdx.x & 63;
    const int p = lane >> 4;          // edge slot 0..3
    const int u = lane & 15;          // channels u*8 .. u*8+7
    const int cb = u * 2;             // float4 index within a 32-float4 row

    const float4* xlm4 = (const float4*)(xl + (size_t)m * N * 128);
    const float4* xrm4 = (const float4*)(xr + (size_t)m * N * 128);

    const v8 attL = load8((const float4*)att, cb);
    const v8 weL  = load8((const float4*)We, cb);
    const v8 xiL  = load8(xrm4, n * 32 + cb);

    float base_, lsum;
    f32x2 acc0, acc1, acc2, acc3;
    {   // self-loop: all 4 slots compute it; each contributes 0.25x (exact)
        const float sw = self_w[n];
        const v8 xj = load8(xlm4, n * 32 + cb);
        const f32x2 swv = (f32x2){sw, sw};
        f32x2 qa = (f32x2){0.f, 0.f}, qb = (f32x2){0.f, 0.f};
        #pragma unroll
        for (int i = 0; i < 4; ++i) {
            const f32x2 v = __builtin_elementwise_fma(swv, weL.h[i], xiL.h[i]) + xj.h[i];
            const f32x2 av = __builtin_elementwise_abs(v);
            qa = __builtin_elementwise_fma(attL.h[i], v, qa);
            qb = __builtin_elementwise_fma(attL.h[i], av, qb);
        }
        float q = fmaf(QA_C, qa[0] + qa[1], QB_C * (qb[0] + qb[1]));
        base_ = reduce8(q);
        lsum = 0.25f;
        const f32x2 qv = (f32x2){0.25f, 0.25f};
        acc0 = xj.h[0] * qv; acc1 = xj.h[1] * qv;
        acc2 = xj.h[2] * qv; acc3 = xj.h[3] * qv;
    }

    const int beg = offs[n], end = offs[n + 1];
    for (int e0 = beg; e0 < end; e0 += 4) {
        const int idx = e0 + p;
        const bool valid = idx < end;
        const int2 pr = pairs[valid ? idx : (end - 1)];
        const int src = pr.x;
        const float w = __int_as_float(pr.y);
        const v8 xj = load8(xlm4, src * 32 + cb);
        const f32x2 wv = (f32x2){w, w};
        f32x2 qa = (f32x2){0.f, 0.f}, qb = (f32x2){0.f, 0.f};
        #pragma unroll
        for (int i = 0; i < 4; ++i) {
            const f32x2 v = __builtin_elementwise_fma(wv, weL.h[i], xiL.h[i]) + xj.h[i];
            const f32x2 av = __builtin_elementwise_abs(v);
            qa = __builtin_elementwise_fma(attL.h[i], v, qa);
            qb = __builtin_elementwise_fma(attL.h[i], av, qb);
        }
        float q = fmaf(QA_C, qa[0] + qa[1], QB_C * (qb[0] + qb[1]));
        q = reduce8(q);
        float t = EXP2F(q - base_);
        t = valid ? t : 0.f;
        lsum += t;
        const f32x2 tv = (f32x2){t, t};
        acc0 = __builtin_elementwise_fma(tv, xj.h[0], acc0);
        acc1 = __builtin_elementwise_fma(tv, xj.h[1], acc1);
        acc2 = __builtin_elementwise_fma(tv, xj.h[2], acc2);
        acc3 = __builtin_elementwise_fma(tv, xj.h[3], acc3);
    }

    // combine the 4 edge slots (lanes l, l+16, l+32, l+48 share channels)
    lsum += __shfl_xor(lsum, 16, 64);
    lsum += __shfl_xor(lsum, 32, 64);
    #define CMB(a) \
        a[0] += __shfl_xor(a[0], 16, 64); a[0] += __shfl_xor(a[0], 32, 64); \
        a[1] += __shfl_xor(a[1], 16, 64); a[1] += __shfl_xor(a[1], 32, 64)
    CMB(acc0); CMB(acc1); CMB(acc2); CMB(acc3);
    #undef CMB

    if (p == 0) {
        const float inv = 1.f / (lsum + EPS_C);
        const v8 bi = load8((const float4*)bias, cb);
        const f32x2 iv = (f32x2){inv, inv};
        f32x2 o0 = __builtin_elementwise_fma(acc0, iv, bi.h[0]);
        f32x2 o1 = __builtin_elementwise_fma(acc1, iv, bi.h[1]);
        f32x2 o2 = __builtin_elementwise_fma(acc2, iv, bi.h[2]);
        f32x2 o3 = __builtin_elementwise_fma(acc3, iv, bi.h[3]);
        float o[8] = {o0[0], o0[1], o1[0], o1[1], o2[0], o2[1], o3[0], o3[1]};
        #pragma unroll
        for (int i = 0; i < 8; ++i) o[i] = o[i] > 0.f ? o[i] : (__expf(o[i]) - 1.f);
        float4* ob = (float4*)(out + (size_t)m * N * 128);
        ob[n * 32 + cb]     = make_float4(o[0], o[1], o[2], o[3]);
        ob[n * 32 + cb + 1] = make_float4(o[4], o[5], o[6], o[7]);
    }
}

// ---------------- launch ----------------

extern "C" void kernel_launch(void* const* d_in, const int* in_sizes, int n_in,
                              void* d_out, int out_size, void* d_ws, size_t ws_size,
                              hipStream_t stream) {
    const float* x    = (const float*)d_in[0];
    const int*   ei   = (const int*)d_in[1];
    const float* ew   = (const float*)d_in[2];
    const float* Wl1  = (const float*)d_in[3];
    const float* Wr1  = (const float*)d_in[4];
    const float* att1 = (const float*)d_in[5];
    const float* We1  = (const float*)d_in[6];
    const float* b1   = (const float*)d_in[7];
    const float* Wl2  = (const float*)d_in[8];
    const float* Wr2  = (const float*)d_in[9];
    const float* att2 = (const float*)d_in[10];
    const float* We2  = (const float*)d_in[11];
    const float* b2   = (const float*)d_in[12];

    const int E = in_sizes[1] / 2;
    const int N = 5000;                 // fixed by setup_inputs
    const int R = out_size / 128;       // M*N rows
    const int M = R / N;                // B*T = 16

    char* ws = (char*)d_ws;
    size_t off = 0;
    auto alloc = [&](size_t bytes) {
        char* p = ws + off;
        off = (off + bytes + 255) & ~(size_t)255;
        return p;
    };
    int*   cnt    = (int*)  alloc((size_t)3 * N * 4);   // cnt | wsum | cursor (1 memset)
    float* wsum   = (float*)(cnt + N);
    int*   cursor = cnt + 2 * N;
    float* selfw  = (float*)alloc((size_t)N * 4);
    int*   offs   = (int*)  alloc((size_t)(N + 1) * 4);
    int2*  pairs  = (int2*) alloc((size_t)E * 8);
    uint4* wf1    = (uint4*)alloc((size_t)2 * 2048 * 16);   // K=64: 64 KB
    uint4* wf2    = (uint4*)alloc((size_t)4 * 2048 * 16);   // K=128: 128 KB
    float* bufA   = (float*)alloc((size_t)R * 128 * 4);
    float* bufB   = (float*)alloc((size_t)R * 128 * 4);
    float* bufC   = (float*)alloc((size_t)R * 128 * 4);

    hipMemsetAsync(cnt, 0, (size_t)3 * N * 4, stream);

    int eb = (E + 255) / 256;
    degree_kernel<<<eb, 256, 0, stream>>>(ei, ew, E, cnt, wsum);
    scan_kernel<<<1, 1024, 0, stream>>>(cnt, wsum, N, E, offs, selfw);
    scatter_kernel<<<eb, 256, 0, stream>>>(ei, ew, E, offs, cursor, pairs);
    wprep_kernel<64><<<8, 256, 0, stream>>>(Wl1, Wr1, wf1);
    wprep_kernel<128><<<16, 256, 0, stream>>>(Wl2, Wr2, wf2);

    const int gb = R / 64;
    const int tb = 2 * ((N + 3) / 4) * 8;   // 20000 blocks: XCD-swizzled task map

    // layer 1: K=64
    gemm_mfma_kernel<64><<<gb, 256, 0, stream>>>(x, wf1, bufA, bufB);
    edge_kernel<<<tb, 256, 0, stream>>>(bufA, bufB, offs, pairs, selfw,
                                        att1, We1, b1, bufC, N, M);
    // layer 2: K=128
    gemm_mfma_kernel<128><<<gb, 256, 0, stream>>>(bufC, wf2, bufA, bufB);
    edge_kernel<<<tb, 256, 0, stream>>>(bufA, bufB, offs, pairs, selfw,
                                        att2, We2, b2, (float*)d_out, N, M);
}